// Round 1
// baseline (504.065 us; speedup 1.0000x reference)
//
#include <hip/hip_runtime.h>
#include <float.h>

#define NPT   4096
#define EMB   512
#define NH    8
#define HD    64
#define KSPLIT 16   // k range split for score kernel -> 16*64 = 1024 blocks

// ---------------------------------------------------------------------------
// 1) pack adj (int32 0/1, [N][N]) into bitmask [N][N/32]
// ---------------------------------------------------------------------------
__global__ __launch_bounds__(256) void pack_adj_kernel(const int* __restrict__ adj,
                                                       unsigned* __restrict__ bits) {
    int gid = blockIdx.x * 256 + threadIdx.x;          // N * (N/32) words
    int q = gid >> 7;                                   // N/32 = 128 words per row
    int w = gid & 127;
    const int4* p = (const int4*)(adj + (size_t)q * NPT + w * 32);
    unsigned m = 0;
#pragma unroll
    for (int i = 0; i < 8; ++i) {
        int4 v = p[i];
        m |= (v.x != 0 ? 1u : 0u) << (i * 4 + 0);
        m |= (v.y != 0 ? 1u : 0u) << (i * 4 + 1);
        m |= (v.z != 0 ? 1u : 0u) << (i * 4 + 2);
        m |= (v.w != 0 ? 1u : 0u) << (i * 4 + 3);
    }
    bits[gid] = m;
}

// ---------------------------------------------------------------------------
// 2) C[n][e] = sum_i x[n][i] * W[e][i]   (x @ W^T), f32, 64x64 tile, BK=16
//    gridDim.z selects (WQ->Q, WK->K, WV->V)
// ---------------------------------------------------------------------------
__global__ __launch_bounds__(256) void gemm_qkv(const float* __restrict__ x,
                                                const float* __restrict__ WQ,
                                                const float* __restrict__ WK,
                                                const float* __restrict__ WV,
                                                float* __restrict__ Q,
                                                float* __restrict__ K,
                                                float* __restrict__ V) {
    const float* W;
    float* C;
    if (blockIdx.z == 0)      { W = WQ; C = Q; }
    else if (blockIdx.z == 1) { W = WK; C = K; }
    else                      { W = WV; C = V; }

    __shared__ float Xs[16][68];   // [i][n], pad 68 keeps 16B alignment
    __shared__ float Ws[16][68];   // [i][e]

    const int tid = threadIdx.x;
    const int tx = tid & 15, ty = tid >> 4;
    const int eb = blockIdx.x * 64;
    const int nb = blockIdx.y * 64;

    float acc[4][4] = {};

    for (int k0 = 0; k0 < EMB; k0 += 16) {
        __syncthreads();
        {
            int n  = tid >> 2;
            int i4 = (tid & 3) * 4;
            float4 xv = *(const float4*)(x + (size_t)(nb + n) * EMB + k0 + i4);
            Xs[i4 + 0][n] = xv.x; Xs[i4 + 1][n] = xv.y;
            Xs[i4 + 2][n] = xv.z; Xs[i4 + 3][n] = xv.w;
            float4 wv = *(const float4*)(W + (size_t)(eb + n) * EMB + k0 + i4);
            Ws[i4 + 0][n] = wv.x; Ws[i4 + 1][n] = wv.y;
            Ws[i4 + 2][n] = wv.z; Ws[i4 + 3][n] = wv.w;
        }
        __syncthreads();
#pragma unroll
        for (int i = 0; i < 16; ++i) {
            float4 a = *(const float4*)&Xs[i][ty * 4];
            float4 b = *(const float4*)&Ws[i][tx * 4];
            acc[0][0] += a.x * b.x; acc[0][1] += a.x * b.y; acc[0][2] += a.x * b.z; acc[0][3] += a.x * b.w;
            acc[1][0] += a.y * b.x; acc[1][1] += a.y * b.y; acc[1][2] += a.y * b.z; acc[1][3] += a.y * b.w;
            acc[2][0] += a.z * b.x; acc[2][1] += a.z * b.y; acc[2][2] += a.z * b.z; acc[2][3] += a.z * b.w;
            acc[3][0] += a.w * b.x; acc[3][1] += a.w * b.y; acc[3][2] += a.w * b.z; acc[3][3] += a.w * b.w;
        }
    }
#pragma unroll
    for (int qi = 0; qi < 4; ++qi) {
        float4 v = make_float4(acc[qi][0], acc[qi][1], acc[qi][2], acc[qi][3]);
        *(float4*)(C + (size_t)(nb + ty * 4 + qi) * EMB + eb + tx * 4) = v;
    }
}

// ---------------------------------------------------------------------------
// 3) masked argmax of Q_h @ K_h^T over k, per 64-q tile and 1/KSPLIT k range.
//    scores are raw dots (scaling/energy/softmax are argmax-invariant).
// ---------------------------------------------------------------------------
__global__ __launch_bounds__(256) void score_argmax(const float* __restrict__ Q,
                                                    const float* __restrict__ K,
                                                    const unsigned* __restrict__ bits,
                                                    float* __restrict__ pval,
                                                    int* __restrict__ pidx) {
    const int ks  = blockIdx.x;           // 0..KSPLIT-1
    const int qb  = blockIdx.y * 64;
    const int tid = threadIdx.x;
    const int tx = tid & 15, ty = tid >> 4;
    const int KRANGE = NPT / KSPLIT;      // 256
    const int NKT = KRANGE / 64;          // 4 k-tiles of 64

    __shared__ float Qs[64][68];          // [d][q]
    __shared__ float Ks[64][68];          // [d][k]
    __shared__ float rv[64][16];
    __shared__ int   ri[64][16];

    for (int h = 0; h < NH; ++h) {
        __syncthreads();                  // previous h done with Qs + red buffers
        {   // stage Qs[d][q] = Q[qb+q][h*64+d]
            int d4 = (tid & 15) * 4;
            int r0 = tid >> 4;
#pragma unroll
            for (int rr = 0; rr < 4; ++rr) {
                int q = r0 + rr * 16;
                float4 v = *(const float4*)(Q + (size_t)(qb + q) * EMB + h * HD + d4);
                Qs[d4 + 0][q] = v.x; Qs[d4 + 1][q] = v.y;
                Qs[d4 + 2][q] = v.z; Qs[d4 + 3][q] = v.w;
            }
        }
        float bestv[4];
        int   besti[4];
#pragma unroll
        for (int qi = 0; qi < 4; ++qi) { bestv[qi] = -FLT_MAX; besti[qi] = 0; }

        for (int kt = 0; kt < NKT; ++kt) {
            const int kbase = ks * KRANGE + kt * 64;
            __syncthreads();              // previous Ks reads done (also covers Qs staging on kt==0)
            {   // stage Ks[d][k] = K[kbase+k][h*64+d]
                int d4 = (tid & 15) * 4;
                int r0 = tid >> 4;
#pragma unroll
                for (int rr = 0; rr < 4; ++rr) {
                    int k = r0 + rr * 16;
                    float4 v = *(const float4*)(K + (size_t)(kbase + k) * EMB + h * HD + d4);
                    Ks[d4 + 0][k] = v.x; Ks[d4 + 1][k] = v.y;
                    Ks[d4 + 2][k] = v.z; Ks[d4 + 3][k] = v.w;
                }
            }
            __syncthreads();

            float acc[4][4] = {};
#pragma unroll 4
            for (int d = 0; d < 64; ++d) {
                float4 a = *(const float4*)&Qs[d][ty * 4];
                float4 b = *(const float4*)&Ks[d][tx * 4];
                acc[0][0] += a.x * b.x; acc[0][1] += a.x * b.y; acc[0][2] += a.x * b.z; acc[0][3] += a.x * b.w;
                acc[1][0] += a.y * b.x; acc[1][1] += a.y * b.y; acc[1][2] += a.y * b.z; acc[1][3] += a.y * b.w;
                acc[2][0] += a.z * b.x; acc[2][1] += a.z * b.y; acc[2][2] += a.z * b.z; acc[2][3] += a.z * b.w;
                acc[3][0] += a.w * b.x; acc[3][1] += a.w * b.y; acc[3][2] += a.w * b.z; acc[3][3] += a.w * b.w;
            }

            // adjacency bits for this thread's 4q x 4k block
#pragma unroll
            for (int qi = 0; qi < 4; ++qi) {
                unsigned word = bits[(size_t)(qb + ty * 4 + qi) * (NPT / 32) + (kbase >> 5) + (tx >> 3)];
                unsigned m4 = (word >> ((tx & 7) * 4)) & 0xF;
#pragma unroll
                for (int kj = 0; kj < 4; ++kj) {
                    if ((m4 >> kj) & 1) {
                        float s = acc[qi][kj];
                        if (s > bestv[qi]) { bestv[qi] = s; besti[qi] = kbase + tx * 4 + kj; }
                    }
                }
            }
        }

        // per-head cross-thread reduction over tx
        __syncthreads();
#pragma unroll
        for (int qi = 0; qi < 4; ++qi) {
            rv[ty * 4 + qi][tx] = bestv[qi];
            ri[ty * 4 + qi][tx] = besti[qi];
        }
        __syncthreads();
        if (tid < 64) {
            float bv = -FLT_MAX; int bi = 0;
#pragma unroll
            for (int j = 0; j < 16; ++j) {
                if (rv[tid][j] > bv) { bv = rv[tid][j]; bi = ri[tid][j]; }
            }
            pval[((size_t)h * KSPLIT + ks) * NPT + qb + tid] = bv;
            pidx[((size_t)h * KSPLIT + ks) * NPT + qb + tid] = bi;
        }
    }
}

// ---------------------------------------------------------------------------
// 4) reduce k-split partials, gather winner V row * (1/NH)
// ---------------------------------------------------------------------------
__global__ __launch_bounds__(128) void gather_out(const float* __restrict__ V,
                                                  const float* __restrict__ pval,
                                                  const int* __restrict__ pidx,
                                                  float* __restrict__ out) {
    const int q = blockIdx.x;
    const int tid = threadIdx.x;
    __shared__ int widx[NH];
    if (tid < NH) {
        float bv = -FLT_MAX; int bi = 0;
        for (int ks = 0; ks < KSPLIT; ++ks) {
            size_t off = ((size_t)tid * KSPLIT + ks) * NPT + q;
            float v = pval[off];
            if (v > bv) { bv = v; bi = pidx[off]; }
        }
        widx[tid] = bi;
    }
    __syncthreads();
    const int h = tid >> 4;
    const int d4 = (tid & 15) * 4;
    const int k = widx[h];
    float4 v = *(const float4*)(V + (size_t)k * EMB + h * HD + d4);
    v.x *= 0.125f; v.y *= 0.125f; v.z *= 0.125f; v.w *= 0.125f;
    *(float4*)(out + (size_t)q * EMB + h * HD + d4) = v;
}

// ---------------------------------------------------------------------------
extern "C" void kernel_launch(void* const* d_in, const int* in_sizes, int n_in,
                              void* d_out, int out_size, void* d_ws, size_t ws_size,
                              hipStream_t stream) {
    const float* x   = (const float*)d_in[0];
    const int*   adj = (const int*)d_in[1];
    const float* WQ  = (const float*)d_in[2];
    const float* WK  = (const float*)d_in[3];
    const float* WV  = (const float*)d_in[4];
    // d_in[5] (we) and d_in[6] (be) are mathematically dead:
    // energy is constant along k -> softmax-shift-invariant -> argmax unchanged.
    float* out = (float*)d_out;

    char* ws = (char*)d_ws;
    const size_t MAT = (size_t)NPT * EMB * sizeof(float);   // 8 MB
    float*    Q    = (float*)(ws);
    float*    K    = (float*)(ws + MAT);
    float*    V    = (float*)(ws + 2 * MAT);
    unsigned* bits = (unsigned*)(ws + 3 * MAT);                         // 2 MB
    float*    pval = (float*)(ws + 3 * MAT + (size_t)NPT * 128 * 4);    // 2 MB
    int*      pidx = (int*)(ws + 3 * MAT + (size_t)NPT * 128 * 4
                               + (size_t)NH * KSPLIT * NPT * 4);        // 2 MB

    pack_adj_kernel<<<dim3(NPT * 128 / 256), dim3(256), 0, stream>>>(adj, bits);
    gemm_qkv<<<dim3(EMB / 64, NPT / 64, 3), dim3(256), 0, stream>>>(x, WQ, WK, WV, Q, K, V);
    score_argmax<<<dim3(KSPLIT, NPT / 64), dim3(256), 0, stream>>>(Q, K, bits, pval, pidx);
    gather_out<<<dim3(NPT), dim3(128), 0, stream>>>(V, pval, pidx, out);
}

// Round 2
// 435.443 us; speedup vs baseline: 1.1576x; 1.1576x over previous
//
#include <hip/hip_runtime.h>
#include <float.h>

#define NPT    4096
#define EMB    512
#define NH     8
#define HD     64
#define KSPLIT 16     // score k-range split -> grid 16 x 32 = 512 blocks = 2/CU

// ---------------------------------------------------------------------------
// 1) pack adj (int32 0/1, [N][N]) into bitmask [N][N/32]
// ---------------------------------------------------------------------------
__global__ __launch_bounds__(256) void pack_adj_kernel(const int* __restrict__ adj,
                                                       unsigned* __restrict__ bits) {
    int gid = blockIdx.x * 256 + threadIdx.x;          // N * (N/32) words
    int q = gid >> 7;                                   // 128 words per row
    int w = gid & 127;
    const int4* p = (const int4*)(adj + (size_t)q * NPT + w * 32);
    unsigned m = 0;
#pragma unroll
    for (int i = 0; i < 8; ++i) {
        int4 v = p[i];
        m |= (v.x != 0 ? 1u : 0u) << (i * 4 + 0);
        m |= (v.y != 0 ? 1u : 0u) << (i * 4 + 1);
        m |= (v.z != 0 ? 1u : 0u) << (i * 4 + 2);
        m |= (v.w != 0 ? 1u : 0u) << (i * 4 + 3);
    }
    bits[gid] = m;
}

// ---------------------------------------------------------------------------
// 2) batched transpose: in[R][512] -> out[512][R] for x, WQ, WK, WV (z=0..3)
//    64x64 tiles, LDS pad 65 (bank-conflict-free both phases, <=2-way)
// ---------------------------------------------------------------------------
__global__ __launch_bounds__(256) void transpose4(const float* __restrict__ x,
                                                  const float* __restrict__ wq,
                                                  const float* __restrict__ wk,
                                                  const float* __restrict__ wv,
                                                  float* __restrict__ xT,
                                                  float* __restrict__ wqT,
                                                  float* __restrict__ wkT,
                                                  float* __restrict__ wvT) {
    const float* in; float* out; int R;
    int z = blockIdx.z;
    if (z == 0)      { in = x;  out = xT;  R = NPT; }
    else if (z == 1) { in = wq; out = wqT; R = EMB; }
    else if (z == 2) { in = wk; out = wkT; R = EMB; }
    else             { in = wv; out = wvT; R = EMB; }
    int rb = blockIdx.y * 64, cb = blockIdx.x * 64;
    if (rb >= R) return;

    __shared__ float Ts[64][65];
    int tid = threadIdx.x;
    int r = tid >> 4, c4 = (tid & 15) * 4;
#pragma unroll
    for (int i = 0; i < 4; ++i) {
        float4 v = *(const float4*)(in + (size_t)(rb + r + 16 * i) * EMB + cb + c4);
        Ts[r + 16 * i][c4 + 0] = v.x; Ts[r + 16 * i][c4 + 1] = v.y;
        Ts[r + 16 * i][c4 + 2] = v.z; Ts[r + 16 * i][c4 + 3] = v.w;
    }
    __syncthreads();
#pragma unroll
    for (int i = 0; i < 4; ++i) {
        int oc = r + 16 * i;   // input col within tile = output row
        float4 v = make_float4(Ts[c4 + 0][oc], Ts[c4 + 1][oc],
                               Ts[c4 + 2][oc], Ts[c4 + 3][oc]);
        *(float4*)(out + (size_t)(cb + oc) * R + rb + c4) = v;
    }
}

// ---------------------------------------------------------------------------
// 3) rank-1 GEMM: Out[r][c] = sum_k A[k][r] * B[k][c], f32.
//    Tile 64r x 128c, BK=16, 256 threads, 4x8 per thread.
//    z=0: Qt = wqT' x xT  -> Qt[512][4096]
//    z=1: Kt = wkT' x xT  -> Kt[512][4096]
//    z=2: V  = xT'  x wvT -> V [4096][512]   (row-major, for gather)
//    All LDS traffic conflict-free: staging is identity-layout float4 copies;
//    a-reads broadcast over tx; b-reads stride 16B -> 2-way (free).
// ---------------------------------------------------------------------------
__global__ __launch_bounds__(256) void gemm_rank1(const float* __restrict__ xT,
                                                  const float* __restrict__ wqT,
                                                  const float* __restrict__ wkT,
                                                  const float* __restrict__ wvT,
                                                  float* __restrict__ Qt,
                                                  float* __restrict__ Kt,
                                                  float* __restrict__ V) {
    const float *A, *B; float* O;
    int sA, sB, sO, rb, cb;
    int b = blockIdx.x, z = blockIdx.z;
    if (z < 2) {
        A = (z == 0) ? wqT : wkT; B = xT; O = (z == 0) ? Qt : Kt;
        sA = EMB; sB = NPT; sO = NPT;
        rb = (b & 7) * 64; cb = (b >> 3) * 128;      // 8 x 32 blocks
    } else {
        A = xT; B = wvT; O = V;
        sA = NPT; sB = EMB; sO = EMB;
        rb = (b & 63) * 64; cb = (b >> 6) * 128;     // 64 x 4 blocks
    }

    __shared__ float As[16][64];
    __shared__ float Bs[16][128];
    const int tid = threadIdx.x;
    const int tx = tid & 15, ty = tid >> 4;

    float acc[4][8] = {};   // [r_i][c: ch*4+cj]

    for (int k0 = 0; k0 < EMB; k0 += 16) {
        __syncthreads();
        {   // As: 1024 floats = 256 float4, 1/thread
            int row = tid >> 4, col4 = (tid & 15) * 4;
            *(float4*)&As[row][col4] = *(const float4*)(A + (size_t)(k0 + row) * sA + rb + col4);
            // Bs: 2048 floats = 512 float4, 2/thread
#pragma unroll
            for (int i = 0; i < 2; ++i) {
                int fi = tid + i * 256;
                int brow = fi >> 5, bcol4 = (fi & 31) * 4;
                *(float4*)&Bs[brow][bcol4] = *(const float4*)(B + (size_t)(k0 + brow) * sB + cb + bcol4);
            }
        }
        __syncthreads();
#pragma unroll 4
        for (int kk = 0; kk < 16; ++kk) {
            float4 a4 = *(const float4*)&As[kk][ty * 4];
            float4 b0 = *(const float4*)&Bs[kk][tx * 4];
            float4 b1 = *(const float4*)&Bs[kk][64 + tx * 4];
            float a[4] = {a4.x, a4.y, a4.z, a4.w};
            float bb[8] = {b0.x, b0.y, b0.z, b0.w, b1.x, b1.y, b1.z, b1.w};
#pragma unroll
            for (int i = 0; i < 4; ++i)
#pragma unroll
                for (int j = 0; j < 8; ++j)
                    acc[i][j] += a[i] * bb[j];
        }
    }
#pragma unroll
    for (int i = 0; i < 4; ++i)
#pragma unroll
        for (int ch = 0; ch < 2; ++ch) {
            float4 v = make_float4(acc[i][ch * 4 + 0], acc[i][ch * 4 + 1],
                                   acc[i][ch * 4 + 2], acc[i][ch * 4 + 3]);
            *(float4*)(O + (size_t)(rb + ty * 4 + i) * sO + cb + ch * 64 + tx * 4) = v;
        }
}

// ---------------------------------------------------------------------------
// 4) masked argmax of Q_h @ K_h^T. 128q x 128k tile, 8x8 per thread as
//    (4+4)x(4+4). Qt/Kt are [e][n] so staging is a straight float4 copy.
//    Cross-tx reduction via shfl_xor butterflies (no LDS).
// ---------------------------------------------------------------------------
__global__ __launch_bounds__(256) void score_argmax(const float* __restrict__ Qt,
                                                    const float* __restrict__ Kt,
                                                    const unsigned* __restrict__ bits,
                                                    float* __restrict__ pval,
                                                    int* __restrict__ pidx) {
    const int ks  = blockIdx.x;            // 0..KSPLIT-1
    const int qb  = blockIdx.y * 128;
    const int tid = threadIdx.x;
    const int tx  = tid & 15, ty = tid >> 4;
    const int KRANGE = NPT / KSPLIT;       // 256 -> 2 k-tiles of 128

    __shared__ float Qs[64][128];
    __shared__ float Ks[64][128];

    for (int h = 0; h < NH; ++h) {
        __syncthreads();                   // prev head done reading Qs
        {   // stage Qs[d][q] <- Qt[h*64+d][qb+q] : 2048 float4, 8/thread
#pragma unroll
            for (int i = 0; i < 8; ++i) {
                int fi = tid + i * 256;
                int row = fi >> 5, col4 = (fi & 31) * 4;
                *(float4*)&Qs[row][col4] =
                    *(const float4*)(Qt + (size_t)(h * HD + row) * NPT + qb + col4);
            }
        }

        float bestv[8];
        int   besti[8];
#pragma unroll
        for (int i = 0; i < 8; ++i) { bestv[i] = -FLT_MAX; besti[i] = 0; }

        for (int kt = 0; kt < 2; ++kt) {
            const int kbase = ks * KRANGE + kt * 128;
            __syncthreads();               // prev Ks readers done (covers Qs stage on kt==0)
            {   // stage Ks[d][k] <- Kt[h*64+d][kbase+k]
#pragma unroll
                for (int i = 0; i < 8; ++i) {
                    int fi = tid + i * 256;
                    int row = fi >> 5, col4 = (fi & 31) * 4;
                    *(float4*)&Ks[row][col4] =
                        *(const float4*)(Kt + (size_t)(h * HD + row) * NPT + kbase + col4);
                }
            }
            __syncthreads();

            float acc[8][8] = {};          // [q: qh*4+qi][k: kh*4+kj]
#pragma unroll 4
            for (int d = 0; d < 64; ++d) {
                float4 a0 = *(const float4*)&Qs[d][ty * 4];
                float4 a1 = *(const float4*)&Qs[d][64 + ty * 4];
                float4 b0 = *(const float4*)&Ks[d][tx * 4];
                float4 b1 = *(const float4*)&Ks[d][64 + tx * 4];
                float a[8] = {a0.x, a0.y, a0.z, a0.w, a1.x, a1.y, a1.z, a1.w};
                float bb[8] = {b0.x, b0.y, b0.z, b0.w, b1.x, b1.y, b1.z, b1.w};
#pragma unroll
                for (int qi = 0; qi < 8; ++qi)
#pragma unroll
                    for (int kj = 0; kj < 8; ++kj)
                        acc[qi][kj] += a[qi] * bb[kj];
            }

            // masked running argmax (k visited in ascending order per thread)
#pragma unroll
            for (int qi = 0; qi < 8; ++qi) {
                int q = qb + (qi >> 2) * 64 + ty * 4 + (qi & 3);
                const unsigned* rowb = bits + (size_t)q * (NPT / 32) + (kbase >> 5) + (tx >> 3);
#pragma unroll
                for (int kh = 0; kh < 2; ++kh) {
                    unsigned m = (rowb[kh * 2] >> ((tx & 7) * 4)) & 0xF;
#pragma unroll
                    for (int kj = 0; kj < 4; ++kj) {
                        if ((m >> kj) & 1) {
                            float s = acc[qi][kh * 4 + kj];
                            if (s > bestv[qi]) {
                                bestv[qi] = s;
                                besti[qi] = kbase + kh * 64 + tx * 4 + kj;
                            }
                        }
                    }
                }
            }
        }

        // reduce across tx (16 lanes) with shfl butterflies; smaller idx on tie
#pragma unroll
        for (int qi = 0; qi < 8; ++qi) {
            float v = bestv[qi]; int bi = besti[qi];
#pragma unroll
            for (int off = 1; off < 16; off <<= 1) {
                float ov = __shfl_xor(v, off);
                int   oi = __shfl_xor(bi, off);
                if (ov > v || (ov == v && oi < bi)) { v = ov; bi = oi; }
            }
            if (tx == 0) {
                int q = qb + (qi >> 2) * 64 + ty * 4 + (qi & 3);
                size_t o = ((size_t)h * KSPLIT + ks) * NPT + q;
                pval[o] = v; pidx[o] = bi;
            }
        }
    }
}

// ---------------------------------------------------------------------------
// 5) reduce k-split partials, gather winner V row * (1/NH)
// ---------------------------------------------------------------------------
__global__ __launch_bounds__(128) void gather_out(const float* __restrict__ V,
                                                  const float* __restrict__ pval,
                                                  const int* __restrict__ pidx,
                                                  float* __restrict__ out) {
    const int q = blockIdx.x;
    const int tid = threadIdx.x;
    __shared__ int widx[NH];
    if (tid < NH) {
        float bv = -FLT_MAX; int bi = 0;
        for (int ks = 0; ks < KSPLIT; ++ks) {
            size_t off = ((size_t)tid * KSPLIT + ks) * NPT + q;
            float v = pval[off];
            if (v > bv) { bv = v; bi = pidx[off]; }
        }
        widx[tid] = bi;
    }
    __syncthreads();
    const int h = tid >> 4;
    const int d4 = (tid & 15) * 4;
    const int k = widx[h];
    float4 v = *(const float4*)(V + (size_t)k * EMB + h * HD + d4);
    v.x *= 0.125f; v.y *= 0.125f; v.z *= 0.125f; v.w *= 0.125f;
    *(float4*)(out + (size_t)q * EMB + h * HD + d4) = v;
}

// ---------------------------------------------------------------------------
extern "C" void kernel_launch(void* const* d_in, const int* in_sizes, int n_in,
                              void* d_out, int out_size, void* d_ws, size_t ws_size,
                              hipStream_t stream) {
    const float* x   = (const float*)d_in[0];
    const int*   adj = (const int*)d_in[1];
    const float* WQ  = (const float*)d_in[2];
    const float* WK  = (const float*)d_in[3];
    const float* WV  = (const float*)d_in[4];
    // we/be are mathematically dead: energy is constant along k ->
    // softmax-shift-invariant -> argmax unchanged.
    float* out = (float*)d_out;

    char* ws = (char*)d_ws;
    const size_t MB = 1u << 20;
    float*    xT   = (float*)(ws);               // 8 MB   (dead after gemm)
    float*    wqT  = (float*)(ws + 8 * MB);      // 1 MB
    float*    wkT  = (float*)(ws + 9 * MB);      // 1 MB
    float*    wvT  = (float*)(ws + 10 * MB);     // 1 MB
    float*    Qt   = (float*)(ws + 11 * MB);     // 8 MB  [512][4096]
    float*    Kt   = (float*)(ws + 19 * MB);     // 8 MB  [512][4096]
    float*    V    = (float*)(ws + 27 * MB);     // 8 MB  [4096][512]
    unsigned* bits = (unsigned*)(ws + 35 * MB);  // 2 MB
    float*    pval = (float*)(ws);               // 2 MB, aliases dead xT
    int*      pidx = (int*)(ws + 2 * MB);        // 2 MB, aliases dead xT

    pack_adj_kernel<<<dim3(NPT * 128 / 256), dim3(256), 0, stream>>>(adj, bits);
    transpose4<<<dim3(8, 64, 4), dim3(256), 0, stream>>>(x, WQ, WK, WV, xT, wqT, wkT, wvT);
    gemm_rank1<<<dim3(256, 1, 3), dim3(256), 0, stream>>>(xT, wqT, wkT, wvT, Qt, Kt, V);
    score_argmax<<<dim3(KSPLIT, NPT / 128), dim3(256), 0, stream>>>(Qt, Kt, bits, pval, pidx);
    gather_out<<<dim3(NPT), dim3(128), 0, stream>>>(V, pval, pidx, out);
}

// Round 3
// 325.895 us; speedup vs baseline: 1.5467x; 1.3361x over previous
//
#include <hip/hip_runtime.h>
#include <hip/hip_bf16.h>
#include <float.h>

#define NPT    4096
#define EMB    512
#define NH     8
#define HD     64
#define KSPLIT 32     // score k-range split: KRANGE = 128

typedef __attribute__((ext_vector_type(8))) short bf16x8;
typedef __attribute__((ext_vector_type(4))) float f32x4;

// ---------------------------------------------------------------------------
// 1) pack adj (int32 0/1, [N][N]) into bitmask [N][N/32]
// ---------------------------------------------------------------------------
__global__ __launch_bounds__(256) void pack_adj_kernel(const int* __restrict__ adj,
                                                       unsigned* __restrict__ bits) {
    int gid = blockIdx.x * 256 + threadIdx.x;
    int q = gid >> 7;
    int w = gid & 127;
    const int4* p = (const int4*)(adj + (size_t)q * NPT + w * 32);
    unsigned m = 0;
#pragma unroll
    for (int i = 0; i < 8; ++i) {
        int4 v = p[i];
        m |= (v.x != 0 ? 1u : 0u) << (i * 4 + 0);
        m |= (v.y != 0 ? 1u : 0u) << (i * 4 + 1);
        m |= (v.z != 0 ? 1u : 0u) << (i * 4 + 2);
        m |= (v.w != 0 ? 1u : 0u) << (i * 4 + 3);
    }
    bits[gid] = m;
}

// ---------------------------------------------------------------------------
// 2) batched transpose: in[R][512] -> out[512][R] for x, WQ, WK, WV
// ---------------------------------------------------------------------------
__global__ __launch_bounds__(256) void transpose4(const float* __restrict__ x,
                                                  const float* __restrict__ wq,
                                                  const float* __restrict__ wk,
                                                  const float* __restrict__ wv,
                                                  float* __restrict__ xT,
                                                  float* __restrict__ wqT,
                                                  float* __restrict__ wkT,
                                                  float* __restrict__ wvT) {
    const float* in; float* out; int R;
    int z = blockIdx.z;
    if (z == 0)      { in = x;  out = xT;  R = NPT; }
    else if (z == 1) { in = wq; out = wqT; R = EMB; }
    else if (z == 2) { in = wk; out = wkT; R = EMB; }
    else             { in = wv; out = wvT; R = EMB; }
    int rb = blockIdx.y * 64, cb = blockIdx.x * 64;
    if (rb >= R) return;

    __shared__ float Ts[64][65];
    int tid = threadIdx.x;
    int r = tid >> 4, c4 = (tid & 15) * 4;
#pragma unroll
    for (int i = 0; i < 4; ++i) {
        float4 v = *(const float4*)(in + (size_t)(rb + r + 16 * i) * EMB + cb + c4);
        Ts[r + 16 * i][c4 + 0] = v.x; Ts[r + 16 * i][c4 + 1] = v.y;
        Ts[r + 16 * i][c4 + 2] = v.z; Ts[r + 16 * i][c4 + 3] = v.w;
    }
    __syncthreads();
#pragma unroll
    for (int i = 0; i < 4; ++i) {
        int oc = r + 16 * i;
        float4 v = make_float4(Ts[c4 + 0][oc], Ts[c4 + 1][oc],
                               Ts[c4 + 2][oc], Ts[c4 + 3][oc]);
        *(float4*)(out + (size_t)(cb + oc) * R + rb + c4) = v;
    }
}

// ---------------------------------------------------------------------------
// helper: exact 3-way bf16 split of an f32 (hi+mid+lo covers all 24 bits)
// ---------------------------------------------------------------------------
__device__ __forceinline__ void split3(float a, unsigned short& h,
                                       unsigned short& m, unsigned short& l) {
    __hip_bfloat16 bh = __float2bfloat16(a);
    float fh = __bfloat162float(bh);
    float r1 = a - fh;
    __hip_bfloat16 bm = __float2bfloat16(r1);
    float fm = __bfloat162float(bm);
    float r2 = r1 - fm;
    __hip_bfloat16 bl = __float2bfloat16(r2);
    h = *reinterpret_cast<unsigned short*>(&bh);
    m = *reinterpret_cast<unsigned short*>(&bm);
    l = *reinterpret_cast<unsigned short*>(&bl);
}

// ---------------------------------------------------------------------------
// 3) projections. Out[n][e] = sum_k xT[k][n] * wT[k][e].
//    z=0 -> Q3 bf16 planes [3][NH][NPT][HD]; z=1 -> K3; z=2 -> V f32 [n][e]
// ---------------------------------------------------------------------------
__global__ __launch_bounds__(256) void gemm_qkv(const float* __restrict__ xT,
                                                const float* __restrict__ wqT,
                                                const float* __restrict__ wkT,
                                                const float* __restrict__ wvT,
                                                unsigned short* __restrict__ Q3,
                                                unsigned short* __restrict__ K3,
                                                float* __restrict__ V) {
    int b = blockIdx.x, z = blockIdx.z;
    const float* B = (z == 0) ? wqT : (z == 1) ? wkT : wvT;
    unsigned short* O3 = (z == 0) ? Q3 : K3;
    const int rb = (b & 63) * 64;       // n
    const int cb = (b >> 6) * 128;      // e

    __shared__ float As[16][64];
    __shared__ float Bs[16][128];
    const int tid = threadIdx.x;
    const int tx = tid & 15, ty = tid >> 4;

    float acc[4][8] = {};

    for (int k0 = 0; k0 < EMB; k0 += 16) {
        __syncthreads();
        {
            int row = tid >> 4, col4 = (tid & 15) * 4;
            *(float4*)&As[row][col4] = *(const float4*)(xT + (size_t)(k0 + row) * NPT + rb + col4);
#pragma unroll
            for (int i = 0; i < 2; ++i) {
                int fi = tid + i * 256;
                int brow = fi >> 5, bcol4 = (fi & 31) * 4;
                *(float4*)&Bs[brow][bcol4] = *(const float4*)(B + (size_t)(k0 + brow) * EMB + cb + bcol4);
            }
        }
        __syncthreads();
#pragma unroll 4
        for (int kk = 0; kk < 16; ++kk) {
            float4 a4 = *(const float4*)&As[kk][ty * 4];
            float4 b0 = *(const float4*)&Bs[kk][tx * 4];
            float4 b1 = *(const float4*)&Bs[kk][64 + tx * 4];
            float a[4] = {a4.x, a4.y, a4.z, a4.w};
            float bb[8] = {b0.x, b0.y, b0.z, b0.w, b1.x, b1.y, b1.z, b1.w};
#pragma unroll
            for (int i = 0; i < 4; ++i)
#pragma unroll
                for (int j = 0; j < 8; ++j)
                    acc[i][j] += a[i] * bb[j];
        }
    }

    if (z == 2) {
#pragma unroll
        for (int i = 0; i < 4; ++i)
#pragma unroll
            for (int ch = 0; ch < 2; ++ch) {
                float4 v = make_float4(acc[i][ch * 4 + 0], acc[i][ch * 4 + 1],
                                       acc[i][ch * 4 + 2], acc[i][ch * 4 + 3]);
                *(float4*)(V + (size_t)(rb + ty * 4 + i) * EMB + cb + ch * 64 + tx * 4) = v;
            }
    } else {
#pragma unroll
        for (int i = 0; i < 4; ++i)
#pragma unroll
            for (int ch = 0; ch < 2; ++ch) {
                int n = rb + ty * 4 + i;
                int e = cb + ch * 64 + tx * 4;
                int h = e >> 6, d = e & 63;
                ushort4 ph, pm, pl;
                split3(acc[i][ch * 4 + 0], ph.x, pm.x, pl.x);
                split3(acc[i][ch * 4 + 1], ph.y, pm.y, pl.y);
                split3(acc[i][ch * 4 + 2], ph.z, pm.z, pl.z);
                split3(acc[i][ch * 4 + 3], ph.w, pm.w, pl.w);
                size_t base = ((size_t)h * NPT + n) * HD + d;
                const size_t PL = (size_t)NH * NPT * HD;
                *(ushort4*)(O3 + base)          = ph;
                *(ushort4*)(O3 + PL + base)     = pm;
                *(ushort4*)(O3 + 2 * PL + base) = pl;
            }
    }
}

// ---------------------------------------------------------------------------
// 4) masked argmax of scores via bf16x3 MFMA (6 plane products, f32-exact
//    to ~2e-6 abs). A = K (m=k), B = Q (n=q). Block: 4 waves x 64q, 128k range.
// ---------------------------------------------------------------------------
__global__ __launch_bounds__(256, 2) void score_mfma(const unsigned short* __restrict__ Q3,
                                                     const unsigned short* __restrict__ K3,
                                                     const unsigned* __restrict__ bits,
                                                     float* __restrict__ pval,
                                                     int* __restrict__ pidx) {
    const int ks  = blockIdx.x;              // 0..KSPLIT-1, KRANGE=128
    const int qb  = blockIdx.y * 256;
    const int tid = threadIdx.x;
    const int wv  = tid >> 6;
    const int lane = tid & 63;
    const int m    = lane & 15;              // fragment row/col index
    const int quad = lane >> 4;
    const size_t PL = (size_t)NH * NPT * HD; // plane stride (elements)

    // K tile staged: [plane][k(128)][72 shorts] (64 data + 8 pad -> 144B rows)
    __shared__ unsigned short Ks[3 * 128 * 72];   // 55296 B

    const int kq = qb + wv * 64;             // this wave's q base

    for (int h = 0; h < NH; ++h) {
        __syncthreads();                     // prev head done reading Ks
#pragma unroll
        for (int i = 0; i < 12; ++i) {       // 3072 16B chunks, 12/thread
            int c = tid + i * 256;
            int p = c >> 10, rem = c & 1023;
            int k = rem >> 3, dq = rem & 7;
            const unsigned short* src = K3 + ((size_t)p * PL)
                + ((size_t)h * NPT + ks * 128 + k) * HD + dq * 8;
            unsigned short* dst = Ks + (p * 128 + k) * 72 + dq * 8;
            *(int4*)dst = *(const int4*)src;
        }
        // persistent Q fragments: [nt][dchunk][plane], B-layout: n=lane&15, d=quad*8+j
        bf16x8 qf[4][2][3];
#pragma unroll
        for (int nt = 0; nt < 4; ++nt)
#pragma unroll
            for (int dc = 0; dc < 2; ++dc)
#pragma unroll
                for (int p = 0; p < 3; ++p)
                    qf[nt][dc][p] = *(const bf16x8*)(Q3 + (size_t)p * PL
                        + ((size_t)h * NPT + kq + nt * 16 + m) * HD + dc * 32 + quad * 8);
        __syncthreads();

        float bestv[4]; int besti[4];
#pragma unroll
        for (int nt = 0; nt < 4; ++nt) { bestv[nt] = -FLT_MAX; besti[nt] = 0; }

        for (int kst = 0; kst < 4; ++kst) {  // 32 k per step
            bf16x8 kf[2][2][3];              // A-layout: m=lane&15, d=quad*8+j
#pragma unroll
            for (int mt = 0; mt < 2; ++mt)
#pragma unroll
                for (int dc = 0; dc < 2; ++dc)
#pragma unroll
                    for (int p = 0; p < 3; ++p)
                        kf[mt][dc][p] = *(const bf16x8*)(Ks
                            + (p * 128 + kst * 32 + mt * 16 + m) * 72 + dc * 32 + quad * 8);

            f32x4 acc[2][4];
#pragma unroll
            for (int mt = 0; mt < 2; ++mt)
#pragma unroll
                for (int nt = 0; nt < 4; ++nt) {
                    f32x4 a = {0.f, 0.f, 0.f, 0.f};
#pragma unroll
                    for (int dc = 0; dc < 2; ++dc) {
                        a = __builtin_amdgcn_mfma_f32_16x16x32_bf16(kf[mt][dc][0], qf[nt][dc][0], a, 0, 0, 0);
                        a = __builtin_amdgcn_mfma_f32_16x16x32_bf16(kf[mt][dc][0], qf[nt][dc][1], a, 0, 0, 0);
                        a = __builtin_amdgcn_mfma_f32_16x16x32_bf16(kf[mt][dc][1], qf[nt][dc][0], a, 0, 0, 0);
                        a = __builtin_amdgcn_mfma_f32_16x16x32_bf16(kf[mt][dc][1], qf[nt][dc][1], a, 0, 0, 0);
                        a = __builtin_amdgcn_mfma_f32_16x16x32_bf16(kf[mt][dc][0], qf[nt][dc][2], a, 0, 0, 0);
                        a = __builtin_amdgcn_mfma_f32_16x16x32_bf16(kf[mt][dc][2], qf[nt][dc][0], a, 0, 0, 0);
                    }
                    acc[mt][nt] = a;
                }

            // epilogue: C col=lane&15 -> q; row=(lane>>4)*4+reg -> k
            const int kbase = ks * 128 + kst * 32;
#pragma unroll
            for (int nt = 0; nt < 4; ++nt) {
                int q = kq + nt * 16 + m;
                unsigned w = bits[(size_t)q * (NPT / 32) + (kbase >> 5)];
#pragma unroll
                for (int mt = 0; mt < 2; ++mt) {
                    int k0 = mt * 16 + quad * 4;
                    f32x4 a = acc[mt][nt];
#pragma unroll
                    for (int r = 0; r < 4; ++r) {
                        if ((w >> (k0 + r)) & 1u) {
                            float s = a[r];
                            if (s > bestv[nt]) { bestv[nt] = s; besti[nt] = kbase + k0 + r; }
                        }
                    }
                }
            }
        }

        // reduce across quad groups (lanes sharing lane&15); smaller idx on tie
#pragma unroll
        for (int nt = 0; nt < 4; ++nt) {
            float v = bestv[nt]; int bi = besti[nt];
#pragma unroll
            for (int off = 16; off < 64; off <<= 1) {
                float ov = __shfl_xor(v, off);
                int   oi = __shfl_xor(bi, off);
                if (ov > v || (ov == v && oi < bi)) { v = ov; bi = oi; }
            }
            if (quad == 0) {
                size_t o = ((size_t)h * KSPLIT + ks) * NPT + kq + nt * 16 + m;
                pval[o] = v; pidx[o] = bi;
            }
        }
    }
}

// ---------------------------------------------------------------------------
// 5) reduce k-split partials, gather winner V row * (1/NH)
// ---------------------------------------------------------------------------
__global__ __launch_bounds__(128) void gather_out(const float* __restrict__ V,
                                                  const float* __restrict__ pval,
                                                  const int* __restrict__ pidx,
                                                  float* __restrict__ out) {
    const int q = blockIdx.x;
    const int tid = threadIdx.x;
    __shared__ int widx[NH];
    if (tid < NH) {
        float bv = -FLT_MAX; int bi = 0;
        for (int ks = 0; ks < KSPLIT; ++ks) {
            size_t off = ((size_t)tid * KSPLIT + ks) * NPT + q;
            float v = pval[off];
            if (v > bv) { bv = v; bi = pidx[off]; }
        }
        widx[tid] = bi;
    }
    __syncthreads();
    const int h = tid >> 4;
    const int d4 = (tid & 15) * 4;
    const int k = widx[h];
    float4 v = *(const float4*)(V + (size_t)k * EMB + h * HD + d4);
    v.x *= 0.125f; v.y *= 0.125f; v.z *= 0.125f; v.w *= 0.125f;
    *(float4*)(out + (size_t)q * EMB + h * HD + d4) = v;
}

// ---------------------------------------------------------------------------
extern "C" void kernel_launch(void* const* d_in, const int* in_sizes, int n_in,
                              void* d_out, int out_size, void* d_ws, size_t ws_size,
                              hipStream_t stream) {
    const float* x   = (const float*)d_in[0];
    const int*   adj = (const int*)d_in[1];
    const float* WQ  = (const float*)d_in[2];
    const float* WK  = (const float*)d_in[3];
    const float* WV  = (const float*)d_in[4];
    // we/be are dead: energy is constant along k -> argmax unchanged.
    float* out = (float*)d_out;

    char* ws = (char*)d_ws;
    const size_t MB = 1u << 20;
    float*          xT   = (float*)(ws);                // 8 MB (dead after gemm)
    float*          wqT  = (float*)(ws + 8 * MB);       // 1 MB
    float*          wkT  = (float*)(ws + 9 * MB);       // 1 MB
    float*          wvT  = (float*)(ws + 10 * MB);      // 1 MB
    unsigned short* Q3   = (unsigned short*)(ws + 11 * MB);  // 12 MB [3][8][4096][64]
    unsigned short* K3   = (unsigned short*)(ws + 23 * MB);  // 12 MB
    float*          V    = (float*)(ws + 35 * MB);      // 8 MB [4096][512]
    unsigned*       bits = (unsigned*)(ws + 43 * MB);   // 2 MB
    float*          pval = (float*)(ws);                // 4 MB, aliases dead xT
    int*            pidx = (int*)(ws + 4 * MB);         // 4 MB, aliases dead xT

    pack_adj_kernel<<<dim3(NPT * 128 / 256), dim3(256), 0, stream>>>(adj, bits);
    transpose4<<<dim3(8, 64, 4), dim3(256), 0, stream>>>(x, WQ, WK, WV, xT, wqT, wkT, wvT);
    gemm_qkv<<<dim3(256, 1, 3), dim3(256), 0, stream>>>(xT, wqT, wkT, wvT, Q3, K3, V);
    score_mfma<<<dim3(KSPLIT, NPT / 256), dim3(256), 0, stream>>>(Q3, K3, bits, pval, pidx);
    gather_out<<<dim3(NPT), dim3(128), 0, stream>>>(V, pval, pidx, out);
}